// Round 1
// 342.376 us; speedup vs baseline: 1.0296x; 1.0296x over previous
//
#include <hip/hip_runtime.h>
#include <math.h>

// Problem constants (fixed by setup_inputs)
#define BN    4096
#define DD    1024
#define CC    1000
#define MM    32768
#define ROWS_CAP 32768   // worst-case B + mem_ptr
#define SIMLD 1024       // sim row stride (bf16 elements)

// A/B fp8 are stored CHUNK-MAJOR TILED (gemm-native):
//   addr(row, k) = (row>>7)*131072 + (k>>4)*2048 + (row&127)*16 + (k&15)
// so gemm's global_load_lds source is linear in thread id (fully coalesced).

typedef __attribute__((ext_vector_type(8))) int   int8v;
typedef __attribute__((ext_vector_type(16))) float f32x16;

__device__ __forceinline__ float wave_max_f(float v) {
#pragma unroll
  for (int off = 32; off >= 1; off >>= 1) v = fmaxf(v, __shfl_xor(v, off, 64));
  return v;
}
__device__ __forceinline__ float wave_sum_f(float v) {
#pragma unroll
  for (int off = 32; off >= 1; off >>= 1) v += __shfl_xor(v, off, 64);
  return v;
}

// round-to-nearest-even float -> bf16 bits (finite inputs)
__device__ __forceinline__ short f2bf(float f) {
  union { float f; unsigned u; } v; v.f = f;
  unsigned r = v.u + 0x7FFF + ((v.u >> 16) & 1);
  return (short)(r >> 16);
}
__device__ __forceinline__ float bf2f(unsigned short u) {
  union { unsigned u; float f; } v; v.u = ((unsigned)u) << 16;
  return v.f;
}

__device__ __forceinline__ int pack4(float a, float b, float c, float d) {
  int p = __builtin_amdgcn_cvt_pk_fp8_f32(a, b, 0, false);
  p = __builtin_amdgcn_cvt_pk_fp8_f32(c, d, p, true);
  return p;
}

__device__ __forceinline__ void gload16(const unsigned char* g, unsigned char* l) {
  __builtin_amdgcn_global_load_lds(
      (const __attribute__((address_space(1))) unsigned int*)g,
      (__attribute__((address_space(3))) unsigned int*)l, 16, 0, 0);
}

// ---------------------------------------------------------------- class counts
// 512 blocks (2/CU), 32 rows per thread fully unrolled -> pipelined loads.
__global__ __launch_bounds__(256) void count_kernel(const int* __restrict__ labels,
                                                    int* __restrict__ counts) {
  const int c = blockIdx.x * 256 + threadIdx.x;
  if (c >= CC) return;
  const int b0 = blockIdx.y * 32;
  int s = 0;
#pragma unroll
  for (int b = 0; b < 32; ++b) s += labels[(size_t)(b0 + b) * CC + c];
  atomicAdd(&counts[c], s);
}

// ---------------------------------------------------------------- class weights
__global__ __launch_bounds__(1024) void weights_kernel(const int* __restrict__ counts,
                                                       float* __restrict__ weights) {
  const int t = threadIdx.x;
  float w = 0.f;
  if (t < CC) {
    float cnt = (float)counts[t];
    float en = 1.0f - expf(cnt * logf(0.999f));   // 1 - BETA^cnt
    w = (1.0f - 0.999f) / (en + 1e-8f);
  }
  float s = wave_sum_f(w);
  __shared__ float part[16];
  if ((t & 63) == 0) part[t >> 6] = s;
  __syncthreads();
  float tot = 0.f;
#pragma unroll
  for (int i = 0; i < 16; ++i) tot += part[i];
  if (t < CC) weights[t] = w * ((float)CC / tot);
}

// ---------------------------------------------------------------- fused convert to fp8
// Wave-per-row: lane owns 16 consecutive k = one 16B chunk of the tiled layout.
// Rows [0, ROWS_CAP): enhanced row -> A (image rows normalized, mem raw).
// Rows [ROWS_CAP, ROWS_CAP+1024): prompt row -> B (10*invnorm folded, pad 0).
__global__ __launch_bounds__(256) void conv_kernel(const float* __restrict__ img,
                                                   const float* __restrict__ prompts,
                                                   const float* __restrict__ mem,
                                                   const int* __restrict__ memptr,
                                                   unsigned char* __restrict__ A,
                                                   unsigned char* __restrict__ B) {
  const int t = threadIdx.x;
  const int lane = t & 63;
  const int gr = blockIdx.x * 4 + (t >> 6);   // wave-uniform row slot

  const float* src = nullptr;
  unsigned char* dst;
  float extraScale = 1.0f;
  bool needNorm = false;

  if (gr >= ROWS_CAP) {
    const int row = gr - ROWS_CAP;            // B row 0..1023 (pad rows -> zeros)
    dst = B + (size_t)(row >> 7) * 131072 + (size_t)(row & 127) * 16;
    if (row < CC) {
      src = prompts + (size_t)row * DD;
      needNorm = true;
      extraScale = 10.0f;                     // 1/TEMPERATURE folded into B
    }
  } else {
    const int nrows = BN + memptr[0];
    const int padded = (nrows + 127) & ~127;
    if (gr >= padded) return;
    dst = A + (size_t)(gr >> 7) * 131072 + (size_t)(gr & 127) * 16;
    if (gr < nrows) {
      if (gr < BN) { src = img + (size_t)gr * DD; needNorm = true; }
      else         { src = mem + (size_t)(gr - BN) * DD; }
    }                                          // else: pad row -> zeros
  }

  int4 o = {0, 0, 0, 0};
  if (src) {
    const float4* s4 = (const float4*)src + lane * 4;   // 64B per lane
    float4 a = s4[0], b = s4[1], c = s4[2], d = s4[3];
    float sc = extraScale;
    if (needNorm) {
      float ss = a.x * a.x + a.y * a.y + a.z * a.z + a.w * a.w
               + b.x * b.x + b.y * b.y + b.z * b.z + b.w * b.w
               + c.x * c.x + c.y * c.y + c.z * c.z + c.w * c.w
               + d.x * d.x + d.y * d.y + d.z * d.z + d.w * d.w;
      ss = wave_sum_f(ss);
      sc = extraScale * rsqrtf(ss + 1e-24f);
    }
    o.x = pack4(a.x * sc, a.y * sc, a.z * sc, a.w * sc);
    o.y = pack4(b.x * sc, b.y * sc, b.z * sc, b.w * sc);
    o.z = pack4(c.x * sc, c.y * sc, c.z * sc, c.w * sc);
    o.w = pack4(d.x * sc, d.y * sc, d.z * sc, d.w * sc);
  }
  *(int4*)(dst + (size_t)lane * 2048) = o;    // lane = k-chunk index
}

// ---------------------------------------------------------------- MX-fp8 MFMA GEMM
// 128x128 tile, BK=128 bytes, chunk-major LDS (phys = kc*2048 + r*16).
// A/B global layout is pre-tiled, so staging source = tileBase + linear(t):
// every gload16 is a contiguous 1KB wave transaction.
__global__ __launch_bounds__(256) void gemm_mx(const unsigned char* __restrict__ A,
                                               const unsigned char* __restrict__ Bm,
                                               const int* __restrict__ memptr,
                                               short* __restrict__ simbf, int lo) {
  const int f = blockIdx.x;
  const int x = f & 7;
  const int s = f >> 3;
  const int c = s & 7;
  const int rt = (s >> 3) * 8 + x;

  const int nrows = BN + memptr[0];
  const int row0 = rt * 128;                 // local row within chunk
  if (lo + row0 >= nrows) return;
  const int c0 = c * 128;

  __shared__ unsigned char As[16384];
  __shared__ unsigned char Bs[16384];

  const int t = threadIdx.x;
  const int lane = t & 63;
  const int wid = t >> 6;
  const int wm = (wid >> 1) * 64;
  const int wn = (wid & 1) * 64;

  // pre-tiled global bases (tile start = row-major byte offset of tile row 0)
  const unsigned char* gaT = A + (size_t)(lo + row0) * DD;
  const unsigned char* gbT = Bm + (size_t)c0 * DD;
  unsigned char* lA = As + t * 16;
  unsigned char* lB = Bs + t * 16;

  f32x16 acc[2][2] = {};
  const int q = lane >> 5;                   // k-half-of-32 selector
  const int rr = lane & 31;

  for (int k0 = 0; k0 < DD; k0 += 128) {
    const size_t kb = (size_t)k0 * 128;      // tile-local byte offset of this K-step
#pragma unroll
    for (int p = 0; p < 4; ++p)
      gload16(gaT + kb + p * 4096 + t * 16, lA + p * 4096);
#pragma unroll
    for (int p = 0; p < 4; ++p)
      gload16(gbT + kb + p * 4096 + t * 16, lB + p * 4096);
    __syncthreads();
#pragma unroll
    for (int h = 0; h < 2; ++h) {
      int8v af[2], bfv[2];
      const int kc = h * 4 + q * 2;
#pragma unroll
      for (int mi = 0; mi < 2; ++mi) {
        const unsigned char* pa = As + kc * 2048 + (wm + mi * 32 + rr) * 16;
        int4 lo4 = *(const int4*)pa;
        int4 hi4 = *(const int4*)(pa + 2048);
        af[mi][0] = lo4.x; af[mi][1] = lo4.y; af[mi][2] = lo4.z; af[mi][3] = lo4.w;
        af[mi][4] = hi4.x; af[mi][5] = hi4.y; af[mi][6] = hi4.z; af[mi][7] = hi4.w;
      }
#pragma unroll
      for (int ni = 0; ni < 2; ++ni) {
        const unsigned char* pb = Bs + kc * 2048 + (wn + ni * 32 + rr) * 16;
        int4 lo4 = *(const int4*)pb;
        int4 hi4 = *(const int4*)(pb + 2048);
        bfv[ni][0] = lo4.x; bfv[ni][1] = lo4.y; bfv[ni][2] = lo4.z; bfv[ni][3] = lo4.w;
        bfv[ni][4] = hi4.x; bfv[ni][5] = hi4.y; bfv[ni][6] = hi4.z; bfv[ni][7] = hi4.w;
      }
#pragma unroll
      for (int mi = 0; mi < 2; ++mi)
#pragma unroll
        for (int ni = 0; ni < 2; ++ni)
          acc[mi][ni] = __builtin_amdgcn_mfma_scale_f32_32x32x64_f8f6f4(
              af[mi], bfv[ni], acc[mi][ni], 0, 0, 0, 127, 0, 127);
    }
    __syncthreads();
  }

  // C/D layout (32x32): col = lane&31, row = (reg&3) + 8*(reg>>2) + 4*(lane>>5)
  const int cl = lane & 31;
  const int r4 = 4 * (lane >> 5);
#pragma unroll
  for (int mi = 0; mi < 2; ++mi)
#pragma unroll
    for (int ni = 0; ni < 2; ++ni) {
      f32x16 v = acc[mi][ni];
      const int colg = c0 + wn + ni * 32 + cl;
      const int rbase = row0 + wm + mi * 32 + r4;
#pragma unroll
      for (int reg = 0; reg < 16; ++reg) {
        const int rowl = rbase + (reg & 3) + 8 * (reg >> 2);
        simbf[(size_t)rowl * SIMLD + colg] = f2bf(v[reg]);
      }
    }
}

// ---------------------------------------------------------------- per-row epilogue
// One wave per row; lane owns 16 contiguous cols (vectorized loads).
__global__ __launch_bounds__(256) void rowpost_kernel(
    const short* __restrict__ simbf, const int* __restrict__ labels,
    const int* __restrict__ mlabels, const float* __restrict__ weights,
    const int* __restrict__ memptr, float* __restrict__ lps_arr,
    float* __restrict__ valid_arr, int chunk_lo) {
  __shared__ float wlds[1024];
  {
    const int t = threadIdx.x;
#pragma unroll
    for (int i = 0; i < 4; ++i) {
      int c = t + i * 256;
      wlds[c] = (c < CC) ? weights[c] : 0.f;
    }
  }
  __syncthreads();

  const int nrows = BN + memptr[0];
  const int wid = threadIdx.x >> 6;
  const int lane = threadIdx.x & 63;
  const int row = chunk_lo + blockIdx.x * 4 + wid;
  if (row >= ROWS_CAP) return;
  if (row >= nrows) {
    if (lane == 0) { lps_arr[row] = 0.f; valid_arr[row] = 0.f; }
    return;
  }

  const unsigned short* srow = (const unsigned short*)simbf + (size_t)(row - chunk_lo) * SIMLD;
  const int* lrow = (row < BN) ? labels + (size_t)row * CC
                               : mlabels + (size_t)(row - BN) * CC;
  const int cbase = lane * 16;

  // vector loads: sim as 2 x 8xu16, labels as 4 x int4 (guarded tail)
  unsigned short sraw[16];
  *(ulonglong2*)&sraw[0] = *(const ulonglong2*)(srow + cbase);
  *(ulonglong2*)&sraw[8] = *(const ulonglong2*)(srow + cbase + 8);
  int lab[16];
#pragma unroll
  for (int g = 0; g < 4; ++g) {
    int c = cbase + g * 4;
    if (c + 3 < CC) {
      *(int4*)&lab[g * 4] = *(const int4*)(lrow + c);
    } else {
#pragma unroll
      for (int u = 0; u < 4; ++u) lab[g * 4 + u] = (c + u < CC) ? lrow[c + u] : 0;
    }
  }

  float sv[16];
  bool pv[16];
  float vneg[16];
#pragma unroll
  for (int j = 0; j < 16; ++j) {
    int c = cbase + j;
    bool ok = (c < CC);
    float sf = bf2f(sraw[j]);
    bool p = ok && (lab[j] > 0);
    sv[j] = ok ? sf : -INFINITY;
    pv[j] = p;
    vneg[j] = (ok && !p) ? sf : -INFINITY;
  }

  // 10 rounds of max-extraction over negatives -> 10th largest negative
  float v10 = -INFINITY;
  for (int r = 0; r < 10; ++r) {
    float lmx = -INFINITY;
#pragma unroll
    for (int j = 0; j < 16; ++j) lmx = fmaxf(lmx, vneg[j]);
    lmx = wave_max_f(lmx);
#pragma unroll
    for (int j = 0; j < 16; ++j) if (vneg[j] == lmx) vneg[j] = -INFINITY;
    v10 = lmx;
  }

  // masked LSE + weighted sums
  float mmax = -INFINITY;
#pragma unroll
  for (int j = 0; j < 16; ++j) {
    if (pv[j] || sv[j] >= v10) mmax = fmaxf(mmax, sv[j]);
  }
  mmax = wave_max_f(mmax);

  float esum = 0.f, wsum = 0.f, wsim = 0.f;
#pragma unroll
  for (int j = 0; j < 16; ++j) {
    int c = cbase + j;
    if (c < CC) {
      if (pv[j] || sv[j] >= v10) esum += expf(sv[j] - mmax);
      if (pv[j]) { float w = wlds[c]; wsum += w; wsim += w * sv[j]; }
    }
  }
  esum = wave_sum_f(esum);
  wsum = wave_sum_f(wsum);
  wsim = wave_sum_f(wsim);

  if (lane == 0) {
    float lse = mmax + logf(esum);
    bool valid = (wsum > 0.f);
    float lps = valid ? (wsum * lse - wsim) / (wsum + 1e-8f) : 0.f;
    float mult = (row < BN) ? 2.f : 1.f;   // image rows appear twice in enhanced set
    lps_arr[row] = mult * lps;
    valid_arr[row] = valid ? mult : 0.f;
  }
}

// ---------------------------------------------------------------- final reduce
__global__ __launch_bounds__(1024) void reduce_kernel(const float* __restrict__ lps_arr,
                                                      const float* __restrict__ valid_arr,
                                                      float* __restrict__ out) {
  const int t = threadIdx.x;
  const float4* l4 = (const float4*)lps_arr;
  const float4* v4 = (const float4*)valid_arr;
  float s1 = 0.f, s2 = 0.f;
#pragma unroll
  for (int i = 0; i < 8; ++i) {
    float4 a = l4[t + i * 1024];
    float4 b = v4[t + i * 1024];
    s1 += a.x + a.y + a.z + a.w;
    s2 += b.x + b.y + b.z + b.w;
  }
  s1 = wave_sum_f(s1);
  s2 = wave_sum_f(s2);
  __shared__ float p1[16], p2[16];
  if ((t & 63) == 0) { p1[t >> 6] = s1; p2[t >> 6] = s2; }
  __syncthreads();
  if (t == 0) {
    float a = 0.f, b = 0.f;
#pragma unroll
    for (int i = 0; i < 16; ++i) { a += p1[i]; b += p2[i]; }
    out[0] = a / fmaxf(b, 1.0f);
  }
}

// ---------------------------------------------------------------- launcher
extern "C" void kernel_launch(void* const* d_in, const int* in_sizes, int n_in,
                              void* d_out, int out_size, void* d_ws, size_t ws_size,
                              hipStream_t stream) {
  const float* img     = (const float*)d_in[0];
  const float* prompts = (const float*)d_in[1];
  const int*   labels  = (const int*)d_in[2];
  const float* mem     = (const float*)d_in[3];
  const int*   mlabels = (const int*)d_in[4];
  const int*   memptr  = (const int*)d_in[5];
  float* out = (float*)d_out;
  char* ws = (char*)d_ws;

  int*   counts  = (int*)(ws + 0);          // 1000 ints (4096 B reserved)
  float* weights = (float*)(ws + 4096);     // 1000 f
  float* lps_arr = (float*)(ws + 8192);     // 32768 f
  float* val_arr = (float*)(ws + 139264);   // 32768 f
  unsigned char* Bf8 = (unsigned char*)(ws + 270336);    // 1024x1024 fp8 = 1 MiB
  unsigned char* Af8 = (unsigned char*)(ws + 1318912);   // 32768x1024 fp8 = 32 MiB
  const size_t fixed = 1318912 + (size_t)ROWS_CAP * DD;  // 34873344
  short* simbf = (short*)(ws + fixed);

  // sim chunk rows (multiple of 1024 so row-tiles per chunk are a multiple of 8)
  long long avail = (long long)ws_size - (long long)fixed;
  int chunk = (int)(avail / (SIMLD * 2));
  chunk &= ~1023;
  if (chunk < 1024) chunk = 1024;
  if (chunk > ROWS_CAP) chunk = ROWS_CAP;

  hipMemsetAsync(ws, 0, 4096, stream);      // zero counts

  conv_kernel<<<(ROWS_CAP + 1024) / 4, 256, 0, stream>>>(img, prompts, mem, memptr, Af8, Bf8);
  count_kernel<<<dim3((CC + 255) / 256, BN / 32), 256, 0, stream>>>(labels, counts);
  weights_kernel<<<1, 1024, 0, stream>>>(counts, weights);

  for (int lo = 0; lo < ROWS_CAP; lo += chunk) {
    int rows = (ROWS_CAP - lo < chunk) ? (ROWS_CAP - lo) : chunk;
    int rowTiles = rows / 128;              // multiple of 8
    gemm_mx<<<8 * rowTiles, 256, 0, stream>>>(Af8, Bf8, memptr, simbf, lo);
    rowpost_kernel<<<rows / 4, 256, 0, stream>>>(simbf, labels, mlabels, weights, memptr,
                                                 lps_arr, val_arr, lo);
  }
  reduce_kernel<<<1, 1024, 0, stream>>>(lps_arr, val_arr, out);
}

// Round 2
// 331.649 us; speedup vs baseline: 1.0629x; 1.0323x over previous
//
#include <hip/hip_runtime.h>
#include <math.h>

// Problem constants (fixed by setup_inputs)
#define BN    4096
#define DD    1024
#define CC    1000
#define MM    32768
#define ROWS_CAP 32768   // worst-case B + mem_ptr
#define SIMLD 1024       // sim row stride (bf16 elements)

// A/B fp8 are stored CHUNK-MAJOR TILED (gemm-native):
//   addr(row, k) = (row>>7)*131072 + (k>>4)*2048 + (row&127)*16 + (k&15)
// conv writes this layout via an LDS transpose (coalesced both sides);
// gemm's global_load_lds source is linear in thread id (fully coalesced).

#define NGROUP_A 512            // ROWS_CAP / 64
#define NGROUP_B 16             // 1024 / 64
#define NCOUNT   512            // 4 col-blocks x 128 row-blocks

typedef __attribute__((ext_vector_type(8))) int   int8v;
typedef __attribute__((ext_vector_type(16))) float f32x16;

__device__ __forceinline__ float wave_max_f(float v) {
#pragma unroll
  for (int off = 32; off >= 1; off >>= 1) v = fmaxf(v, __shfl_xor(v, off, 64));
  return v;
}
__device__ __forceinline__ float wave_sum_f(float v) {
#pragma unroll
  for (int off = 32; off >= 1; off >>= 1) v += __shfl_xor(v, off, 64);
  return v;
}

// round-to-nearest-even float -> bf16 bits (finite inputs)
__device__ __forceinline__ short f2bf(float f) {
  union { float f; unsigned u; } v; v.f = f;
  unsigned r = v.u + 0x7FFF + ((v.u >> 16) & 1);
  return (short)(r >> 16);
}
__device__ __forceinline__ float bf2f(unsigned short u) {
  union { unsigned u; float f; } v; v.u = ((unsigned)u) << 16;
  return v.f;
}

__device__ __forceinline__ int pack4(float a, float b, float c, float d) {
  int p = __builtin_amdgcn_cvt_pk_fp8_f32(a, b, 0, false);
  p = __builtin_amdgcn_cvt_pk_fp8_f32(c, d, p, true);
  return p;
}

__device__ __forceinline__ void gload16(const unsigned char* g, unsigned char* l) {
  __builtin_amdgcn_global_load_lds(
      (const __attribute__((address_space(1))) unsigned int*)g,
      (__attribute__((address_space(3))) unsigned int*)l, 16, 0, 0);
}

// ---------------------------------------------------------------- conv + count
// Blocks [0, NGROUP_A): 64 enhanced rows -> A tiled fp8 (LDS transpose).
// Blocks [NGROUP_A, NGROUP_A+NGROUP_B): 64 prompt rows -> B tiled fp8.
// Blocks [NGROUP_A+NGROUP_B, +NCOUNT): class-count partial sums (atomic).
__global__ __launch_bounds__(256) void conv_kernel(const float* __restrict__ img,
                                                   const float* __restrict__ prompts,
                                                   const float* __restrict__ mem,
                                                   const int* __restrict__ memptr,
                                                   unsigned char* __restrict__ A,
                                                   unsigned char* __restrict__ B,
                                                   const int* __restrict__ labels,
                                                   int* __restrict__ counts) {
  const int blk = blockIdx.x;

  if (blk >= NGROUP_A + NGROUP_B) {            // ---- count section
    const int ci = blk - (NGROUP_A + NGROUP_B);
    const int c = (ci & 3) * 256 + threadIdx.x;
    if (c >= CC) return;
    const int b0 = (ci >> 2) * 32;
    int s = 0;
#pragma unroll
    for (int b = 0; b < 32; ++b) s += labels[(size_t)(b0 + b) * CC + c];
    atomicAdd(&counts[c], s);
    return;
  }

  // ---- transpose-convert section (64-row group)
  __shared__ unsigned char tile[65536];        // 64 kc-stripes x 1024 B
  const int t = threadIdx.x;
  const int lane = t & 63;
  const int wid = t >> 6;
  const int nrows = BN + memptr[0];
  const int padded = (nrows + 127) & ~127;

  const bool isB = (blk >= NGROUP_A);
  const int g = isB ? (blk - NGROUP_A) : blk;
  const int rowBase = g * 64;
  if (!isB && rowBase >= padded) return;       // never read by gemm

  unsigned char* dstBase = (isB ? B : A)
      + (size_t)(rowBase >> 7) * 131072 + (size_t)(rowBase & 64) * 16;

  for (int i = 0; i < 16; ++i) {
    const int r = wid * 16 + i;                // row slot within group
    const int row = rowBase + r;
    const float* src = nullptr;
    float esc = 1.0f;
    bool needNorm = false;
    if (isB) {
      if (row < CC) { src = prompts + (size_t)row * DD; needNorm = true; esc = 10.0f; }
    } else {
      if (row < BN)         { src = img + (size_t)row * DD; needNorm = true; }
      else if (row < nrows) { src = mem + (size_t)(row - BN) * DD; }
    }
    int4 o = {0, 0, 0, 0};
    if (src) {
      const float4* s4 = (const float4*)src + lane * 4;   // 64B per lane (k = lane*16..)
      float4 a = s4[0], b = s4[1], c = s4[2], d = s4[3];
      float sc = esc;
      if (needNorm) {
        float ss = a.x * a.x + a.y * a.y + a.z * a.z + a.w * a.w
                 + b.x * b.x + b.y * b.y + b.z * b.z + b.w * b.w
                 + c.x * c.x + c.y * c.y + c.z * c.z + c.w * c.w
                 + d.x * d.x + d.y * d.y + d.z * d.z + d.w * d.w;
        ss = wave_sum_f(ss);
        sc = esc * rsqrtf(ss + 1e-24f);
      }
      o.x = pack4(a.x * sc, a.y * sc, a.z * sc, a.w * sc);
      o.y = pack4(b.x * sc, b.y * sc, b.z * sc, b.w * sc);
      o.z = pack4(c.x * sc, c.y * sc, c.z * sc, c.w * sc);
      o.w = pack4(d.x * sc, d.y * sc, d.z * sc, d.w * sc);
    }
    // stripe kc = lane, rotated slot (r+kc)&63 -> distinct chunks per lane
    *(int4*)(tile + lane * 1024 + (((r + lane) & 63) << 4)) = o;
  }
  __syncthreads();

#pragma unroll
  for (int p = 0; p < 16; ++p) {
    const int ochunk = p * 256 + t;            // kc = ochunk>>6 (wave-uniform), rl = lane
    const int kc = ochunk >> 6;
    const int rl = ochunk & 63;
    int4 v = *(const int4*)(tile + kc * 1024 + (((rl + kc) & 63) << 4));
    *(int4*)(dstBase + (size_t)kc * 2048 + rl * 16) = v;   // 1KB contiguous per wave
  }
}

// ---------------------------------------------------------------- MX-fp8 MFMA GEMM
// 128x128 tile, BK=128 bytes, chunk-major LDS (phys = kc*2048 + r*16).
// A/B global layout is pre-tiled, so staging source = tileBase + linear(t):
// every gload16 is a contiguous 1KB wave transaction.
__global__ __launch_bounds__(256) void gemm_mx(const unsigned char* __restrict__ A,
                                               const unsigned char* __restrict__ Bm,
                                               const int* __restrict__ memptr,
                                               short* __restrict__ simbf, int lo) {
  const int f = blockIdx.x;
  const int x = f & 7;
  const int s = f >> 3;
  const int c = s & 7;
  const int rt = (s >> 3) * 8 + x;

  const int nrows = BN + memptr[0];
  const int row0 = rt * 128;                 // local row within chunk
  if (lo + row0 >= nrows) return;
  const int c0 = c * 128;

  __shared__ unsigned char As[16384];
  __shared__ unsigned char Bs[16384];

  const int t = threadIdx.x;
  const int lane = t & 63;
  const int wid = t >> 6;
  const int wm = (wid >> 1) * 64;
  const int wn = (wid & 1) * 64;

  // pre-tiled global bases (tile start = row-major byte offset of tile row 0)
  const unsigned char* gaT = A + (size_t)(lo + row0) * DD;
  const unsigned char* gbT = Bm + (size_t)c0 * DD;
  unsigned char* lA = As + t * 16;
  unsigned char* lB = Bs + t * 16;

  f32x16 acc[2][2] = {};
  const int q = lane >> 5;                   // k-half-of-32 selector
  const int rr = lane & 31;

  for (int k0 = 0; k0 < DD; k0 += 128) {
    const size_t kb = (size_t)k0 * 128;      // tile-local byte offset of this K-step
#pragma unroll
    for (int p = 0; p < 4; ++p)
      gload16(gaT + kb + p * 4096 + t * 16, lA + p * 4096);
#pragma unroll
    for (int p = 0; p < 4; ++p)
      gload16(gbT + kb + p * 4096 + t * 16, lB + p * 4096);
    __syncthreads();
#pragma unroll
    for (int h = 0; h < 2; ++h) {
      int8v af[2], bfv[2];
      const int kc = h * 4 + q * 2;
#pragma unroll
      for (int mi = 0; mi < 2; ++mi) {
        const unsigned char* pa = As + kc * 2048 + (wm + mi * 32 + rr) * 16;
        int4 lo4 = *(const int4*)pa;
        int4 hi4 = *(const int4*)(pa + 2048);
        af[mi][0] = lo4.x; af[mi][1] = lo4.y; af[mi][2] = lo4.z; af[mi][3] = lo4.w;
        af[mi][4] = hi4.x; af[mi][5] = hi4.y; af[mi][6] = hi4.z; af[mi][7] = hi4.w;
      }
#pragma unroll
      for (int ni = 0; ni < 2; ++ni) {
        const unsigned char* pb = Bs + kc * 2048 + (wn + ni * 32 + rr) * 16;
        int4 lo4 = *(const int4*)pb;
        int4 hi4 = *(const int4*)(pb + 2048);
        bfv[ni][0] = lo4.x; bfv[ni][1] = lo4.y; bfv[ni][2] = lo4.z; bfv[ni][3] = lo4.w;
        bfv[ni][4] = hi4.x; bfv[ni][5] = hi4.y; bfv[ni][6] = hi4.z; bfv[ni][7] = hi4.w;
      }
#pragma unroll
      for (int mi = 0; mi < 2; ++mi)
#pragma unroll
        for (int ni = 0; ni < 2; ++ni)
          acc[mi][ni] = __builtin_amdgcn_mfma_scale_f32_32x32x64_f8f6f4(
              af[mi], bfv[ni], acc[mi][ni], 0, 0, 0, 127, 0, 127);
    }
    __syncthreads();
  }

  // C/D layout (32x32): col = lane&31, row = (reg&3) + 8*(reg>>2) + 4*(lane>>5)
  const int cl = lane & 31;
  const int r4 = 4 * (lane >> 5);
#pragma unroll
  for (int mi = 0; mi < 2; ++mi)
#pragma unroll
    for (int ni = 0; ni < 2; ++ni) {
      f32x16 v = acc[mi][ni];
      const int colg = c0 + wn + ni * 32 + cl;
      const int rbase = row0 + wm + mi * 32 + r4;
#pragma unroll
      for (int reg = 0; reg < 16; ++reg) {
        const int rowl = rbase + (reg & 3) + 8 * (reg >> 2);
        simbf[(size_t)rowl * SIMLD + colg] = f2bf(v[reg]);
      }
    }
}

// ---------------------------------------------------------------- per-row epilogue
// One wave per row; lane owns 16 contiguous cols (vectorized loads).
// Class weights are recomputed per block from counts (removes serial 1-block kernel).
__global__ __launch_bounds__(256) void rowpost_kernel(
    const short* __restrict__ simbf, const int* __restrict__ labels,
    const int* __restrict__ mlabels, const int* __restrict__ counts,
    const int* __restrict__ memptr, float* __restrict__ lps_arr,
    float* __restrict__ valid_arr, int chunk_lo) {
  __shared__ float wlds[1024];
  __shared__ float wpart[4];
  {
    const int t = threadIdx.x;
    float wv[4];
    float acc = 0.f;
#pragma unroll
    for (int i = 0; i < 4; ++i) {
      int c = t + i * 256;
      float w = 0.f;
      if (c < CC) {
        float cnt = (float)counts[c];
        float en = 1.0f - expf(cnt * logf(0.999f));   // 1 - BETA^cnt
        w = (1.0f - 0.999f) / (en + 1e-8f);
      }
      wv[i] = w;
      acc += w;
    }
    float s = wave_sum_f(acc);
    if ((t & 63) == 0) wpart[t >> 6] = s;
    __syncthreads();
    float tot = wpart[0] + wpart[1] + wpart[2] + wpart[3];
    float sc = (float)CC / tot;
#pragma unroll
    for (int i = 0; i < 4; ++i) wlds[t + i * 256] = wv[i] * sc;
    __syncthreads();
  }

  const int nrows = BN + memptr[0];
  const int wid = threadIdx.x >> 6;
  const int lane = threadIdx.x & 63;
  const int row = chunk_lo + blockIdx.x * 4 + wid;
  if (row >= ROWS_CAP) return;
  if (row >= nrows) {
    if (lane == 0) { lps_arr[row] = 0.f; valid_arr[row] = 0.f; }
    return;
  }

  const unsigned short* srow = (const unsigned short*)simbf + (size_t)(row - chunk_lo) * SIMLD;
  const int* lrow = (row < BN) ? labels + (size_t)row * CC
                               : mlabels + (size_t)(row - BN) * CC;
  const int cbase = lane * 16;

  // vector loads: sim as 2 x 8xu16, labels as 4 x int4 (guarded tail)
  unsigned short sraw[16];
  *(ulonglong2*)&sraw[0] = *(const ulonglong2*)(srow + cbase);
  *(ulonglong2*)&sraw[8] = *(const ulonglong2*)(srow + cbase + 8);
  int lab[16];
#pragma unroll
  for (int g = 0; g < 4; ++g) {
    int c = cbase + g * 4;
    if (c + 3 < CC) {
      *(int4*)&lab[g * 4] = *(const int4*)(lrow + c);
    } else {
#pragma unroll
      for (int u = 0; u < 4; ++u) lab[g * 4 + u] = (c + u < CC) ? lrow[c + u] : 0;
    }
  }

  float sv[16];
  bool pv[16];
  float vneg[16];
#pragma unroll
  for (int j = 0; j < 16; ++j) {
    int c = cbase + j;
    bool ok = (c < CC);
    float sf = bf2f(sraw[j]);
    bool p = ok && (lab[j] > 0);
    sv[j] = ok ? sf : -INFINITY;
    pv[j] = p;
    vneg[j] = (ok && !p) ? sf : -INFINITY;
  }

  // 10 rounds of max-extraction over negatives -> 10th largest negative
  float v10 = -INFINITY;
  for (int r = 0; r < 10; ++r) {
    float lmx = -INFINITY;
#pragma unroll
    for (int j = 0; j < 16; ++j) lmx = fmaxf(lmx, vneg[j]);
    lmx = wave_max_f(lmx);
#pragma unroll
    for (int j = 0; j < 16; ++j) if (vneg[j] == lmx) vneg[j] = -INFINITY;
    v10 = lmx;
  }

  // masked LSE + weighted sums
  float mmax = -INFINITY;
#pragma unroll
  for (int j = 0; j < 16; ++j) {
    if (pv[j] || sv[j] >= v10) mmax = fmaxf(mmax, sv[j]);
  }
  mmax = wave_max_f(mmax);

  float esum = 0.f, wsum = 0.f, wsim = 0.f;
#pragma unroll
  for (int j = 0; j < 16; ++j) {
    int c = cbase + j;
    if (c < CC) {
      if (pv[j] || sv[j] >= v10) esum += expf(sv[j] - mmax);
      if (pv[j]) { float w = wlds[c]; wsum += w; wsim += w * sv[j]; }
    }
  }
  esum = wave_sum_f(esum);
  wsum = wave_sum_f(wsum);
  wsim = wave_sum_f(wsim);

  if (lane == 0) {
    float lse = mmax + logf(esum);
    bool valid = (wsum > 0.f);
    float lps = valid ? (wsum * lse - wsim) / (wsum + 1e-8f) : 0.f;
    float mult = (row < BN) ? 2.f : 1.f;   // image rows appear twice in enhanced set
    lps_arr[row] = mult * lps;
    valid_arr[row] = valid ? mult : 0.f;
  }
}

// ---------------------------------------------------------------- final reduce
__global__ __launch_bounds__(1024) void reduce_kernel(const float* __restrict__ lps_arr,
                                                      const float* __restrict__ valid_arr,
                                                      float* __restrict__ out) {
  const int t = threadIdx.x;
  const float4* l4 = (const float4*)lps_arr;
  const float4* v4 = (const float4*)valid_arr;
  float s1 = 0.f, s2 = 0.f;
#pragma unroll
  for (int i = 0; i < 8; ++i) {
    float4 a = l4[t + i * 1024];
    float4 b = v4[t + i * 1024];
    s1 += a.x + a.y + a.z + a.w;
    s2 += b.x + b.y + b.z + b.w;
  }
  s1 = wave_sum_f(s1);
  s2 = wave_sum_f(s2);
  __shared__ float p1[16], p2[16];
  if ((t & 63) == 0) { p1[t >> 6] = s1; p2[t >> 6] = s2; }
  __syncthreads();
  if (t == 0) {
    float a = 0.f, b = 0.f;
#pragma unroll
    for (int i = 0; i < 16; ++i) { a += p1[i]; b += p2[i]; }
    out[0] = a / fmaxf(b, 1.0f);
  }
}

// ---------------------------------------------------------------- launcher
extern "C" void kernel_launch(void* const* d_in, const int* in_sizes, int n_in,
                              void* d_out, int out_size, void* d_ws, size_t ws_size,
                              hipStream_t stream) {
  const float* img     = (const float*)d_in[0];
  const float* prompts = (const float*)d_in[1];
  const int*   labels  = (const int*)d_in[2];
  const float* mem     = (const float*)d_in[3];
  const int*   mlabels = (const int*)d_in[4];
  const int*   memptr  = (const int*)d_in[5];
  float* out = (float*)d_out;
  char* ws = (char*)d_ws;

  int*   counts  = (int*)(ws + 0);          // 1000 ints (4096 B reserved)
  float* lps_arr = (float*)(ws + 8192);     // 32768 f
  float* val_arr = (float*)(ws + 139264);   // 32768 f
  unsigned char* Bf8 = (unsigned char*)(ws + 270336);    // 1024x1024 fp8 = 1 MiB
  unsigned char* Af8 = (unsigned char*)(ws + 1318912);   // 32768x1024 fp8 = 32 MiB
  const size_t fixed = 1318912 + (size_t)ROWS_CAP * DD;  // 34873344
  short* simbf = (short*)(ws + fixed);

  // sim chunk rows (multiple of 1024 so row-tiles per chunk are a multiple of 8)
  long long avail = (long long)ws_size - (long long)fixed;
  int chunk = (int)(avail / (SIMLD * 2));
  chunk &= ~1023;
  if (chunk < 1024) chunk = 1024;
  if (chunk > ROWS_CAP) chunk = ROWS_CAP;

  hipMemsetAsync(ws, 0, 4096, stream);      // zero counts

  conv_kernel<<<NGROUP_A + NGROUP_B + NCOUNT, 256, 0, stream>>>(
      img, prompts, mem, memptr, Af8, Bf8, labels, counts);

  for (int lo = 0; lo < ROWS_CAP; lo += chunk) {
    int rows = (ROWS_CAP - lo < chunk) ? (ROWS_CAP - lo) : chunk;
    int rowTiles = rows / 128;              // multiple of 8
    gemm_mx<<<8 * rowTiles, 256, 0, stream>>>(Af8, Bf8, memptr, simbf, lo);
    rowpost_kernel<<<rows / 4, 256, 0, stream>>>(simbf, labels, mlabels, counts, memptr,
                                                 lps_arr, val_arr, lo);
  }
  reduce_kernel<<<1, 1024, 0, stream>>>(lps_arr, val_arr, out);
}